// Round 1
// baseline (339.724 us; speedup 1.0000x reference)
//
#include <hip/hip_runtime.h>

#define L_SEQ  2048
#define DIM    64
#define RAD    128
#define TI     16
#define KCOLS  (TI + 2*RAD)          // 272 staged K rows
#define NBH    48                    // B*H
#define NTILES (L_SEQ / TI)          // 128
#define NBLK   (NBH * NTILES)        // 6144

// Block = one (b,h) x 16-row tile. Thread t owns output cols [4t..4t+3] and
// [1024+4t..1024+4t+3] (float4 stores, fully coalesced). K band staged in LDS
// with XOR swizzle to kill the 256B-stride bank conflict on ds_read_b128.
__global__ __launch_bounds__(256, 2)
void band_scores(const float* __restrict__ Qg, const float* __restrict__ Kg,
                 float* __restrict__ outg) {
    __shared__ float4 sK[KCOLS * (DIM/4)];   // 69632 B, swizzled [col][d4]
    __shared__ float4 sQ[TI * (DIM/4)];      // 4096 B

    const int t = threadIdx.x;

    // XCD-aware bijective swizzle (NBLK % 8 == 0): each XCD gets a contiguous
    // chunk of tiles -> overlapping K bands stay in that XCD's L2.
    const int id  = blockIdx.x;
    const int swz = (id & 7) * (NBLK / 8) + (id >> 3);
    const int bh  = swz / NTILES;
    const int i0  = (swz % NTILES) * TI;

    const float4* K4 = reinterpret_cast<const float4*>(Kg) + (size_t)bh * L_SEQ * (DIM/4);
    const float4* Q4 = reinterpret_cast<const float4*>(Qg) + (size_t)bh * L_SEQ * (DIM/4);
    float* obh = outg + (size_t)bh * L_SEQ * L_SEQ;

    // ---- stage Q tile (16 rows x 64): 256 float4, one per thread
    sQ[t] = Q4[i0 * (DIM/4) + t];

    // ---- stage K band rows [i0-128, i0+143] (clipped): 4352 float4, 17/thread
    const int kbase = i0 - RAD;
#pragma unroll
    for (int it = 0; it < (KCOLS * (DIM/4)) / 256; ++it) {
        int idx = it * 256 + t;
        int col = idx >> 4;          // staged row index 0..271
        int d4  = idx & 15;          // float4 index within row
        int row = kbase + col;
        if (row >= 0 && row < L_SEQ)
            sK[(col << 4) + (d4 ^ ((col >> 2) & 7))] = K4[(size_t)row * (DIM/4) + d4];
    }
    __syncthreads();

    const int c0 = t * 4;            // chunk A columns
    const int c1 = 1024 + t * 4;     // chunk B columns (never in-band together: 1024 > 260)

    for (int rg = 0; rg < TI / 4; ++rg) {
        const int ibase = i0 + rg * 4;
        const int lo = ibase - RAD;
        const int hi = ibase + 3 + RAD;
        const bool doA = (c0 + 3 >= lo) && (c0 <= hi);
        const bool doB = (c1 + 3 >= lo) && (c1 <= hi);

        float acc[4][4];
#pragma unroll
        for (int r = 0; r < 4; ++r)
#pragma unroll
            for (int c = 0; c < 4; ++c) acc[r][c] = 0.f;

        if (doA || doB) {
            const int cb = doA ? c0 : c1;     // at most one chunk active
            int s[4], x[4];
#pragma unroll
            for (int c = 0; c < 4; ++c) {
                int si = cb + c - kbase;      // may be up to 3 out of range at band edges
                si = si < 0 ? 0 : (si > KCOLS - 1 ? KCOLS - 1 : si);  // clamp; masked at store
                s[c] = si << 4;
                x[c] = (si >> 2) & 7;
            }
#pragma unroll
            for (int d4 = 0; d4 < DIM / 4; ++d4) {
                float4 kv[4], qv[4];
#pragma unroll
                for (int c = 0; c < 4; ++c) kv[c] = sK[s[c] + (d4 ^ x[c])];
#pragma unroll
                for (int r = 0; r < 4; ++r) qv[r] = sQ[(((rg << 2) + r) << 4) + d4];
#pragma unroll
                for (int r = 0; r < 4; ++r) {
                    const float qx = qv[r].x, qy = qv[r].y, qz = qv[r].z, qw = qv[r].w;
#pragma unroll
                    for (int c = 0; c < 4; ++c)
                        acc[r][c] += qx * kv[c].x + qy * kv[c].y + qz * kv[c].z + qw * kv[c].w;
                }
            }
        }

        // ---- store 4 rows x (chunk A + chunk B); select-mask (not multiply) so
        // clamped/garbage lanes can't leak NaN. Every element written every call.
#pragma unroll
        for (int r = 0; r < 4; ++r) {
            const int i = ibase + r;
            float4* o4 = reinterpret_cast<float4*>(obh + (size_t)i * L_SEQ);
            float4 vA = make_float4(0.f, 0.f, 0.f, 0.f);
            float4 vB = make_float4(0.f, 0.f, 0.f, 0.f);
            if (doA) {
                vA.x = ((unsigned)(i - (c0 + 0) + RAD) <= 2 * RAD) ? acc[r][0] : 0.f;
                vA.y = ((unsigned)(i - (c0 + 1) + RAD) <= 2 * RAD) ? acc[r][1] : 0.f;
                vA.z = ((unsigned)(i - (c0 + 2) + RAD) <= 2 * RAD) ? acc[r][2] : 0.f;
                vA.w = ((unsigned)(i - (c0 + 3) + RAD) <= 2 * RAD) ? acc[r][3] : 0.f;
            }
            if (doB) {
                vB.x = ((unsigned)(i - (c1 + 0) + RAD) <= 2 * RAD) ? acc[r][0] : 0.f;
                vB.y = ((unsigned)(i - (c1 + 1) + RAD) <= 2 * RAD) ? acc[r][1] : 0.f;
                vB.z = ((unsigned)(i - (c1 + 2) + RAD) <= 2 * RAD) ? acc[r][2] : 0.f;
                vB.w = ((unsigned)(i - (c1 + 3) + RAD) <= 2 * RAD) ? acc[r][3] : 0.f;
            }
            o4[t]       = vA;
            o4[256 + t] = vB;
        }
    }
}

extern "C" void kernel_launch(void* const* d_in, const int* in_sizes, int n_in,
                              void* d_out, int out_size, void* d_ws, size_t ws_size,
                              hipStream_t stream) {
    const float* Q = (const float*)d_in[0];
    const float* K = (const float*)d_in[1];
    float* out = (float*)d_out;
    band_scores<<<NBLK, 256, 0, stream>>>(Q, K, out);
}

// Round 2
// 216.488 us; speedup vs baseline: 1.5693x; 1.5693x over previous
//
#include <hip/hip_runtime.h>

#define L_SEQ  2048
#define D4     16            // DIM/4
#define RAD    128
#define TI     16
#define NBH    48
#define NTILES 128           // L_SEQ/TI
#define NBLK   (NBH * NTILES)
#define NC4    512           // float4 chunks per row
#define NS0    144           // phase-0 staged K rows
#define NS1    128           // phase-1 staged K rows

// Block = one (b,h) x 16-row tile, 256 threads, two column-half phases.
// LDS = 144*256 + 16*256 = 40960 B -> exactly 4 blocks/CU (16 waves).
// Every thread computes ~2 in-band chunks per phase (balanced); zero
// stores for out-of-band chunks issue before the first barrier so they
// overlap staging-load latency.
__global__ __launch_bounds__(256, 4)
void band_scores(const float* __restrict__ Qg, const float* __restrict__ Kg,
                 float* __restrict__ outg)
{
    __shared__ float4 sK[NS0 * D4];   // 36864 B, swizzled: slot = si*16 + (d4 ^ ((si>>2)&7))
    __shared__ float4 sQ[TI * D4];    // 4096 B, swizzled: slot = row*16 + (d4 ^ row)

    const int t  = threadIdx.x;
    const int id = blockIdx.x;
    // bijective XCD swizzle (NBLK % 8 == 0): neighbors-in-tile share an XCD's L2
    const int swz = (id & 7) * (NBLK / 8) + (id >> 3);
    const int bh  = swz >> 7;
    const int i0  = (swz & (NTILES - 1)) * TI;
    const int i04 = i0 >> 2;

    const float4* K4 = reinterpret_cast<const float4*>(Kg) + (size_t)bh * L_SEQ * D4;
    const float4* Q4 = reinterpret_cast<const float4*>(Qg) + (size_t)bh * L_SEQ * D4;
    float4*       O4 = reinterpret_cast<float4*>(outg)     + (size_t)bh * L_SEQ * NC4;

    // ---- stage Q tile (16 rows x 64), swizzled
    {
        const int row = t >> 4, d4 = t & 15;
        const float4 v = Q4[(i0 + row) * D4 + d4];
        sQ[(row << 4) + (d4 ^ row)] = v;
    }

    // ---- stage K phase 0: global rows [i0-128, i0+15] (si = 0..143)
    const int kb0 = i0 - RAD;
#pragma unroll
    for (int itr = 0; itr < 9; ++itr) {
        const int s  = itr * 256 + t;
        const int si = s >> 4, d4 = s & 15;
        int row = kb0 + si;
        row = row < 0 ? 0 : row;            // clamp; clamped slots are never read
        const float4 v = K4[(size_t)row * D4 + d4];
        sK[(si << 4) + (d4 ^ ((si >> 2) & 7))] = v;
    }

    // ---- zero all out-of-band chunks (independent of staging -> overlaps load latency)
#pragma unroll
    for (int rg = 0; rg < 4; ++rg) {
        int L = i04 + rg - 32; L = L < 0 ? 0 : L;          // in-band chunk range [L,H]
        int H = i04 + rg + 32; H = H > NC4 - 1 ? NC4 - 1 : H;
        const int rb = (i0 + rg * 4) * NC4;
#pragma unroll
        for (int wz = 0; wz < 8; ++wz) {
            const int ww = wz * 256 + t;
            const int r = ww >> 9, c = ww & (NC4 - 1);
            if (c < L || c > H)
                O4[rb + r * NC4 + c] = make_float4(0.f, 0.f, 0.f, 0.f);
        }
    }
    __syncthreads();

    // ---- compute phase 0: chunks j4 in [i04+rg-32, i04+3]  (576 items, ~2.25/thread)
    for (int w = t; w < 576; w += 256) {
        const int rg  = w / 144;
        const int rem = w - rg * 144;
        const int cb  = rem >> 2, r = rem & 3;
        const int j4  = i04 + rg - 32 + cb;
        if (cb <= 35 - rg && j4 >= 0) {
            const int rl = rg * 4 + r;
            const int iR = i0 + rl;
            const int sb = (rg + cb) << 2;   // si for c=0 (multiple of 4)
            const int x  = (rg + cb) & 7;    // shared swizzle for all 4 cols
            float ax = 0.f, ay = 0.f, az = 0.f, aw = 0.f;
#pragma unroll
            for (int d4 = 0; d4 < D4; ++d4) {
                const float4 q  = sQ[(rl << 4) + (d4 ^ rl)];
                const int    dk = d4 ^ x;
                const float4 k0 = sK[((sb + 0) << 4) + dk];
                const float4 k1 = sK[((sb + 1) << 4) + dk];
                const float4 k2 = sK[((sb + 2) << 4) + dk];
                const float4 k3 = sK[((sb + 3) << 4) + dk];
                ax += q.x*k0.x + q.y*k0.y + q.z*k0.z + q.w*k0.w;
                ay += q.x*k1.x + q.y*k1.y + q.z*k1.z + q.w*k1.w;
                az += q.x*k2.x + q.y*k2.y + q.z*k2.z + q.w*k2.w;
                aw += q.x*k3.x + q.y*k3.y + q.z*k3.z + q.w*k3.w;
            }
            const int c0 = j4 << 2;
            float4 v;
            v.x = ((unsigned)(iR - (c0 + 0) + RAD) <= 2u * RAD) ? ax : 0.f;
            v.y = ((unsigned)(iR - (c0 + 1) + RAD) <= 2u * RAD) ? ay : 0.f;
            v.z = ((unsigned)(iR - (c0 + 2) + RAD) <= 2u * RAD) ? az : 0.f;
            v.w = ((unsigned)(iR - (c0 + 3) + RAD) <= 2u * RAD) ? aw : 0.f;
            O4[iR * NC4 + j4] = v;
        }
    }
    __syncthreads();   // LDS reads of phase 0 done before overwrite

    // ---- stage K phase 1: global rows [i0+16, i0+143] (si = 0..127)
    const int kb1 = i0 + TI;
#pragma unroll
    for (int itr = 0; itr < 8; ++itr) {
        const int s  = itr * 256 + t;
        const int si = s >> 4, d4 = s & 15;
        int row = kb1 + si;
        row = row > L_SEQ - 1 ? L_SEQ - 1 : row;   // clamp; never read
        const float4 v = K4[(size_t)row * D4 + d4];
        sK[(si << 4) + (d4 ^ ((si >> 2) & 7))] = v;
    }
    __syncthreads();

    // ---- compute phase 1: chunks j4 in [i04+4, i04+rg+32]  (512 items, 2/thread)
    for (int w = t; w < 512; w += 256) {
        const int rg  = w >> 7;
        const int rem = w & 127;
        const int cb  = rem >> 2, r = rem & 3;
        const int j4  = i04 + 4 + cb;
        if (cb <= 28 + rg && j4 <= NC4 - 1) {
            const int rl = rg * 4 + r;
            const int iR = i0 + rl;
            const int sb = cb << 2;
            const int x  = cb & 7;
            float ax = 0.f, ay = 0.f, az = 0.f, aw = 0.f;
#pragma unroll
            for (int d4 = 0; d4 < D4; ++d4) {
                const float4 q  = sQ[(rl << 4) + (d4 ^ rl)];
                const int    dk = d4 ^ x;
                const float4 k0 = sK[((sb + 0) << 4) + dk];
                const float4 k1 = sK[((sb + 1) << 4) + dk];
                const float4 k2 = sK[((sb + 2) << 4) + dk];
                const float4 k3 = sK[((sb + 3) << 4) + dk];
                ax += q.x*k0.x + q.y*k0.y + q.z*k0.z + q.w*k0.w;
                ay += q.x*k1.x + q.y*k1.y + q.z*k1.z + q.w*k1.w;
                az += q.x*k2.x + q.y*k2.y + q.z*k2.z + q.w*k2.w;
                aw += q.x*k3.x + q.y*k3.y + q.z*k3.z + q.w*k3.w;
            }
            const int c0 = j4 << 2;
            float4 v;
            v.x = ((unsigned)(iR - (c0 + 0) + RAD) <= 2u * RAD) ? ax : 0.f;
            v.y = ((unsigned)(iR - (c0 + 1) + RAD) <= 2u * RAD) ? ay : 0.f;
            v.z = ((unsigned)(iR - (c0 + 2) + RAD) <= 2u * RAD) ? az : 0.f;
            v.w = ((unsigned)(iR - (c0 + 3) + RAD) <= 2u * RAD) ? aw : 0.f;
            O4[iR * NC4 + j4] = v;
        }
    }
}

extern "C" void kernel_launch(void* const* d_in, const int* in_sizes, int n_in,
                              void* d_out, int out_size, void* d_ws, size_t ws_size,
                              hipStream_t stream) {
    const float* Q = (const float*)d_in[0];
    const float* K = (const float*)d_in[1];
    float* out = (float*)d_out;
    band_scores<<<NBLK, 256, 0, stream>>>(Q, K, out);
}

// Round 3
// 215.450 us; speedup vs baseline: 1.5768x; 1.0048x over previous
//
#include <hip/hip_runtime.h>

#define L_SEQ  2048
#define D4     16            // DIM/4
#define RAD    128
#define TI     16
#define NBH    48
#define NTILES 128           // L_SEQ/TI
#define NBLK   (NBH * NTILES)
#define NC4    512           // float4 chunks per row
#define NS0    144           // phase-0 staged K rows

// Block = one (b,h) x 16-row tile, 256 threads, two column-half phases.
// LDS = 144*256 + 16*256 = 40960 B -> 4 blocks/CU (16 waves).
// Register blocking: each work item = 4 rows x 4 cols (64 outputs), so one
// d4-iteration costs 8 ds_read_b128 for 64 FMAs (0.5 B/FLOP) -- 2.6x less
// LDS traffic than the 1x4 version, keeping LDS off the critical path.
__global__ __launch_bounds__(256, 4)
void band_scores(const float* __restrict__ Qg, const float* __restrict__ Kg,
                 float* __restrict__ outg)
{
    __shared__ float4 sK[NS0 * D4];   // 36864 B, slot = si*16 + (d4 ^ ((si>>2)&7))
    __shared__ float4 sQ[TI * D4];    // 4096 B,  slot = row*16 + (d4 ^ row)

    const int t  = threadIdx.x;
    const int id = blockIdx.x;
    // bijective XCD swizzle (NBLK % 8 == 0)
    const int swz = (id & 7) * (NBLK / 8) + (id >> 3);
    const int bh  = swz >> 7;
    const int i0  = (swz & (NTILES - 1)) * TI;
    const int i04 = i0 >> 2;

    const float4* K4 = reinterpret_cast<const float4*>(Kg) + (size_t)bh * L_SEQ * D4;
    const float4* Q4 = reinterpret_cast<const float4*>(Qg) + (size_t)bh * L_SEQ * D4;
    float4*       O4 = reinterpret_cast<float4*>(outg)     + (size_t)bh * L_SEQ * NC4;

    // ---- stage Q tile (16 rows x 64), swizzled
    {
        const int row = t >> 4, d4 = t & 15;
        const float4 v = Q4[(i0 + row) * D4 + d4];
        sQ[(row << 4) + (d4 ^ row)] = v;
    }

    // ---- stage K phase 0: global rows [i0-128, i0+15] (si = 0..143)
    const int kb0 = i0 - RAD;
#pragma unroll
    for (int itr = 0; itr < 9; ++itr) {
        const int s  = itr * 256 + t;
        const int si = s >> 4, d4 = s & 15;
        int row = kb0 + si;
        row = row < 0 ? 0 : row;            // clamp; clamped slots never read (guarded)
        const float4 v = K4[(size_t)row * D4 + d4];
        sK[(si << 4) + (d4 ^ ((si >> 2) & 7))] = v;
    }

    // ---- zero all out-of-band chunks (independent of staging -> overlaps load latency)
#pragma unroll
    for (int rg = 0; rg < 4; ++rg) {
        int L = i04 + rg - 32; L = L < 0 ? 0 : L;
        int H = i04 + rg + 32; H = H > NC4 - 1 ? NC4 - 1 : H;
        const int rb = (i0 + rg * 4) * NC4;
#pragma unroll
        for (int wz = 0; wz < 8; ++wz) {
            const int ww = wz * 256 + t;
            const int r = ww >> 9, c = ww & (NC4 - 1);
            if (c < L || c > H)
                O4[rb + r * NC4 + c] = make_float4(0.f, 0.f, 0.f, 0.f);
        }
    }
    __syncthreads();

    // ================= phase 0: 144 items, one per thread t<144 =================
    // item: (rg, cb) -> 4 rows [i0+4rg .. +3] x chunk j4 = i04+rg-32+cb
    {
        const int rg = t / 36;
        const int cb = t - rg * 36;
        const int j4 = i04 + rg - 32 + cb;
        if (t < 144 && cb <= 35 - rg && j4 >= 0) {
            const int rg4 = rg << 2;
            const int sb  = (rg + cb) << 2;   // staged K row base (multiple of 4)
            const int x   = (rg + cb) & 7;
            float acc[4][4];
#pragma unroll
            for (int r = 0; r < 4; ++r)
#pragma unroll
                for (int c = 0; c < 4; ++c) acc[r][c] = 0.f;
#pragma unroll 4
            for (int d4 = 0; d4 < D4; ++d4) {
                const int dk = d4 ^ x;
                float4 kv[4], qv[4];
#pragma unroll
                for (int c = 0; c < 4; ++c) kv[c] = sK[((sb + c) << 4) + dk];
#pragma unroll
                for (int r = 0; r < 4; ++r) qv[r] = sQ[((rg4 + r) << 4) + (d4 ^ (rg4 + r))];
#pragma unroll
                for (int r = 0; r < 4; ++r)
#pragma unroll
                    for (int c = 0; c < 4; ++c)
                        acc[r][c] += qv[r].x * kv[c].x + qv[r].y * kv[c].y
                                   + qv[r].z * kv[c].z + qv[r].w * kv[c].w;
            }
            const int c0 = j4 << 2;
#pragma unroll
            for (int r = 0; r < 4; ++r) {
                const int i = i0 + rg4 + r;
                float4 v;
                v.x = ((unsigned)(i - (c0 + 0) + RAD) <= 2u * RAD) ? acc[r][0] : 0.f;
                v.y = ((unsigned)(i - (c0 + 1) + RAD) <= 2u * RAD) ? acc[r][1] : 0.f;
                v.z = ((unsigned)(i - (c0 + 2) + RAD) <= 2u * RAD) ? acc[r][2] : 0.f;
                v.w = ((unsigned)(i - (c0 + 3) + RAD) <= 2u * RAD) ? acc[r][3] : 0.f;
                O4[i * NC4 + j4] = v;
            }
        }
    }
    __syncthreads();   // phase-0 LDS reads done before overwrite

    // ---- stage K phase 1: global rows [i0+16, i0+143] (si = 0..127)
    const int kb1 = i0 + TI;
#pragma unroll
    for (int itr = 0; itr < 8; ++itr) {
        const int s  = itr * 256 + t;
        const int si = s >> 4, d4 = s & 15;
        int row = kb1 + si;
        row = row > L_SEQ - 1 ? L_SEQ - 1 : row;   // clamp; never read (guarded)
        const float4 v = K4[(size_t)row * D4 + d4];
        sK[(si << 4) + (d4 ^ ((si >> 2) & 7))] = v;
    }
    __syncthreads();

    // ================= phase 1: 128 items, one per thread t<128 =================
    // item: (rg, cb) -> rows [i0+4rg ..] x chunk j4 = i04+4+cb
    {
        const int rg = t >> 5;
        const int cb = t & 31;
        const int j4 = i04 + 4 + cb;
        if (t < 128 && cb <= 28 + rg && j4 <= NC4 - 1) {
            const int rg4 = rg << 2;
            const int sb  = cb << 2;
            const int x   = cb & 7;
            float acc[4][4];
#pragma unroll
            for (int r = 0; r < 4; ++r)
#pragma unroll
                for (int c = 0; c < 4; ++c) acc[r][c] = 0.f;
#pragma unroll 4
            for (int d4 = 0; d4 < D4; ++d4) {
                const int dk = d4 ^ x;
                float4 kv[4], qv[4];
#pragma unroll
                for (int c = 0; c < 4; ++c) kv[c] = sK[((sb + c) << 4) + dk];
#pragma unroll
                for (int r = 0; r < 4; ++r) qv[r] = sQ[((rg4 + r) << 4) + (d4 ^ (rg4 + r))];
#pragma unroll
                for (int r = 0; r < 4; ++r)
#pragma unroll
                    for (int c = 0; c < 4; ++c)
                        acc[r][c] += qv[r].x * kv[c].x + qv[r].y * kv[c].y
                                   + qv[r].z * kv[c].z + qv[r].w * kv[c].w;
            }
            const int c0 = j4 << 2;
#pragma unroll
            for (int r = 0; r < 4; ++r) {
                const int i = i0 + rg4 + r;
                float4 v;
                v.x = ((unsigned)(i - (c0 + 0) + RAD) <= 2u * RAD) ? acc[r][0] : 0.f;
                v.y = ((unsigned)(i - (c0 + 1) + RAD) <= 2u * RAD) ? acc[r][1] : 0.f;
                v.z = ((unsigned)(i - (c0 + 2) + RAD) <= 2u * RAD) ? acc[r][2] : 0.f;
                v.w = ((unsigned)(i - (c0 + 3) + RAD) <= 2u * RAD) ? acc[r][3] : 0.f;
                O4[i * NC4 + j4] = v;
            }
        }
    }
}

extern "C" void kernel_launch(void* const* d_in, const int* in_sizes, int n_in,
                              void* d_out, int out_size, void* d_ws, size_t ws_size,
                              hipStream_t stream) {
    const float* Q = (const float*)d_in[0];
    const float* K = (const float*)d_in[1];
    float* out = (float*)d_out;
    band_scores<<<NBLK, 256, 0, stream>>>(Q, K, out);
}